// Round 13
// baseline (311.182 us; speedup 1.0000x reference)
//
#include <hip/hip_runtime.h>
#include <hip/hip_bf16.h>
#include <math.h>
#include <stdint.h>

#define L_SEQ 4096
#define NB 2
#define NH 16
#define DHEAD 64
#define DM 1024
#define DQKV 3072

typedef __bf16 bf16_t;
typedef __attribute__((ext_vector_type(8))) __bf16 bf16x8;
typedef __attribute__((ext_vector_type(4))) float f32x4;

#define GLD16(gp, lp) __builtin_amdgcn_global_load_lds(                          \
    (const __attribute__((address_space(1))) void*)(gp),                         \
    (__attribute__((address_space(3))) void*)(lp), 16, 0, 0)

template<int N> __device__ __forceinline__ void vmwait() {
    if constexpr (N == 3)      asm volatile("s_waitcnt vmcnt(3)" ::: "memory");
    else if constexpr (N == 2) asm volatile("s_waitcnt vmcnt(2)" ::: "memory");
    else                       asm volatile("s_waitcnt vmcnt(0)" ::: "memory");
}

// ---------------- fused fp32->bf16 weight casts + conn MLP ----------------
__device__ __forceinline__ void cast8(const float* src, bf16_t* dst)
{
    const f32x4* ip = (const f32x4*)src;
    f32x4 a = ip[0], b = ip[1];
    bf16x8 o;
    o[0] = (__bf16)a[0]; o[1] = (__bf16)a[1]; o[2] = (__bf16)a[2]; o[3] = (__bf16)a[3];
    o[4] = (__bf16)b[0]; o[5] = (__bf16)b[1]; o[6] = (__bf16)b[2]; o[7] = (__bf16)b[3];
    *(bf16x8*)dst = o;
}

__device__ __forceinline__ float gelu_exact(float z)
{
    return 0.5f * z * (1.0f + erff(z * 0.7071067811865475f));
}

// blocks 0..1535: wq|wk|wv; 1536..2047: wo; 2048..2063: conn
__global__ __launch_bounds__(256) void fused_cast_kernel(
    const float* __restrict__ wq, const float* __restrict__ wk,
    const float* __restrict__ wv, const float* __restrict__ wo,
    const float* __restrict__ cw1, const float* __restrict__ cb1,
    const float* __restrict__ cw2, const float* __restrict__ cb2,
    const float* __restrict__ cw3, const float* __restrict__ cb3,
    bf16_t* __restrict__ wqkvb, bf16_t* __restrict__ wob,
    float* __restrict__ conn)
{
    const int bid = blockIdx.x;
    const int tid = threadIdx.x;
    const int nW = DM * DM / 8;
    if (bid < 1536) {
        int t = bid * 256 + tid;
        const float* src; int lt;
        if (t < nW)          { src = wq; lt = t; }
        else if (t < 2 * nW) { src = wk; lt = t - nW; }
        else                 { src = wv; lt = t - 2 * nW; }
        cast8(src + (size_t)lt * 8, wqkvb + (size_t)t * 8);
    } else if (bid < 2048) {
        int t = (bid - 1536) * 256 + tid;
        cast8(wo + (size_t)t * 8, wob + (size_t)t * 8);
    } else {
        __shared__ float h1[7][32];
        __shared__ float h2[7][32];
        const int h = bid - 2048;
        const int j = tid;
        if (j < 32) {
            for (int w = 0; w < 7; ++w) {
                float pos = (float)w / 6.0f;
                float z = pos * cw1[h * 32 + j] + cb1[h * 32 + j];
                h1[w][j] = gelu_exact(z);
            }
        }
        __syncthreads();
        if (j < 32) {
            for (int w = 0; w < 7; ++w) {
                float z = cb2[h * 32 + j];
                for (int i = 0; i < 32; ++i) z += h1[w][i] * cw2[((size_t)h * 32 + j) * 32 + i];
                h2[w][j] = gelu_exact(z);
            }
        }
        __syncthreads();
        if (j == 0) {
            float cwt[7];
            float mx = -1e30f;
            for (int w = 0; w < 7; ++w) {
                float z = cb3[h];
                for (int i = 0; i < 32; ++i) z += h2[w][i] * cw3[h * 32 + i];
                cwt[w] = z;
                mx = fmaxf(mx, z);
            }
            float Z = 0.0f;
            for (int w = 0; w < 7; ++w) { cwt[w] = expf(cwt[w] - mx); Z += cwt[w]; }
            for (int w = 0; w < 7; ++w) conn[h * 7 + w] = cwt[w] / Z;
        }
    }
}

// ---------------- QKV GEMM with in-kernel fp32->bf16 A conversion ----------------
// C[8192, NOUT] = cast_bf16(Xf) @ Bw^T.  R11's proven rhythm; only the A staging
// path changes: global f32 loads -> regs -> cvt -> ds_write (B keeps gld_lds).
// Per-tile vm group = [A 2x f32x4 per chunk x2 chunks = 4 loads? no: 2 chunks x
// (2 f32x4) = 4 plain loads + 1 B gld] -- wait, A slice/thread = 16B bf16 = 32B
// f32 = 2 f32x4 per chunk, 2 chunks -> 4 loads + 1 B gld = 5 vm-ops/tile.
// LEDGER (groups fenced by the per-tile asm gates):
//   prologue: issue g0, fence, issue g1, vmwait<5> (drains g0) -> writeA(0).
//   tile t top: vmwait<5> (queue [g(t):5, g(t+1):5] -> drains g(t), keeps g(t+1))
//     -> writeA(t) [t>=1] -> lgkmcnt(0) -> barrier -> reads(t) -> issue g(t+2)
//     -> MFMA(t).  Tail t=NT-1: vmwait<0>.  Never 0 mid-loop.
//   writeA(t) overwrites ring slot t%3, last read at tile t-3..: readers done
//   2 barriers earlier.  B slot (t+2)%3 overwrite safe as in R11.
template<int NOUT>
__global__ __launch_bounds__(512, 4) void gemm_xa(const float* __restrict__ Xf,
                                                  const bf16_t* __restrict__ Bw,
                                                  bf16_t* __restrict__ Cout)
{
    constexpr int K   = 1024;
    constexpr int NT  = K / 32;
    constexpr int ASZ = 256 * 64;          // bytes per A K-tile buffer
    constexpr int BSZ = 128 * 64;
    constexpr int NTN = NOUT / 128;

    extern __shared__ char smem[];         // A: 3*ASZ @0, B: 3*BSZ @3*ASZ

    const int tid  = threadIdx.x;
    const int lane = tid & 63;
    const int wave = tid >> 6;
    const int wm   = (wave >> 1) * 64;
    const int wn   = (wave & 1) * 64;

    const int nwg = gridDim.x;
    int id = blockIdx.x;
    id = (id & 7) * (nwg >> 3) + (id >> 3);
    const int bm = (id / NTN) * 256;
    const int bn = (id % NTN) * 128;

    const int scol = (((tid & 3) ^ ((tid >> 3) & 3)) * 8);
    const int srow = tid >> 2;             // 0..127
    const float*  Ax = Xf + (size_t)(bm + srow) * K + scol;
    const bf16_t* Bg = Bw + (size_t)(bn + srow) * K + scol;

    // A in-flight registers: 2 tiles (parity) x 2 chunks x 2 f32x4
    f32x4 areg[2][2][2];

    auto issueA = [&](int kt) {
        const int s = kt & 1;
#pragma unroll
        for (int c = 0; c < 2; ++c) {
            const float* p = Ax + (size_t)(c * 128) * K + kt * 32;
            areg[s][c][0] = *(const f32x4*)p;
            areg[s][c][1] = *(const f32x4*)(p + 4);
        }
    };
    auto stageB = [&](int kt) {
        char* lb = smem + 3 * ASZ + (kt % 3) * BSZ + tid * 16;
        GLD16(Bg + (size_t)kt * 32, lb);
    };
    auto writeA = [&](int kt) {
        const int s = kt & 1;
        char* la = smem + (kt % 3) * ASZ + tid * 16;
#pragma unroll
        for (int c = 0; c < 2; ++c) {
            f32x4 lo = areg[s][c][0], hi = areg[s][c][1];
            bf16x8 o;
            o[0] = (__bf16)lo[0]; o[1] = (__bf16)lo[1];
            o[2] = (__bf16)lo[2]; o[3] = (__bf16)lo[3];
            o[4] = (__bf16)hi[0]; o[5] = (__bf16)hi[1];
            o[6] = (__bf16)hi[2]; o[7] = (__bf16)hi[3];
            *(bf16x8*)(la + c * 8192) = o;     // ds_write_b128
        }
    };

    f32x4 acc[4][4] = {};

    issueA(0); stageB(0);
    asm volatile("" ::: "memory");             // fence group 0 | group 1
    issueA(1); stageB(1);
    asm volatile("s_waitcnt vmcnt(5)" ::: "memory");   // drain group 0
    writeA(0);

    int aoff[4], boff[4];
#pragma unroll
    for (int m = 0; m < 4; ++m) {
        const int r = wm + m * 16 + (lane & 15);
        aoff[m] = r * 64 + (((lane >> 4) ^ ((r >> 1) & 3)) * 16);
    }
#pragma unroll
    for (int n = 0; n < 4; ++n) {
        const int r = wn + n * 16 + (lane & 15);
        boff[n] = r * 64 + (((lane >> 4) ^ ((r >> 1) & 3)) * 16);
    }

    for (int t = 0; t < NT; ++t) {
        if (t < NT - 1) asm volatile("s_waitcnt vmcnt(5)" ::: "memory");
        else            vmwait<0>();
        if (t >= 1) writeA(t);                 // regs of group t drained above
        asm volatile("s_waitcnt lgkmcnt(0)" ::: "memory");   // publish A writes
        __builtin_amdgcn_s_barrier();
        asm volatile("" ::: "memory");

        const char* Ab = smem + (t % 3) * ASZ;
        const char* Bb = smem + 3 * ASZ + (t % 3) * BSZ;

        bf16x8 af[4], bfr[4];
#pragma unroll
        for (int m = 0; m < 4; ++m) af[m]  = *(const bf16x8*)(Ab + aoff[m]);
#pragma unroll
        for (int n = 0; n < 4; ++n) bfr[n] = *(const bf16x8*)(Bb + boff[n]);

        if (t + 2 < NT) {
            __builtin_amdgcn_sched_barrier(0); // reads issue before new loads
            issueA(t + 2);
            stageB(t + 2);
        }

        __builtin_amdgcn_s_setprio(1);
#pragma unroll
        for (int m = 0; m < 4; ++m)
#pragma unroll
            for (int n = 0; n < 4; ++n)
                acc[m][n] = __builtin_amdgcn_mfma_f32_16x16x32_bf16(af[m], bfr[n], acc[m][n], 0, 0, 0);
        __builtin_amdgcn_s_setprio(0);
    }

    const int r0 = (lane >> 4) * 4;
    const int c0 = lane & 15;
#pragma unroll
    for (int m = 0; m < 4; ++m) {
#pragma unroll
        for (int n = 0; n < 4; ++n) {
            const int col = bn + wn + n * 16 + c0;
#pragma unroll
            for (int r = 0; r < 4; ++r) {
                const int row = bm + wm + m * 16 + r0 + r;
                Cout[(size_t)row * NOUT + col] = (__bf16)acc[m][n][r];
            }
        }
    }
}

// ---------------- R5/R8/R11-proven coarse GEMM (out-proj) ----------------
template<int BM, int BN, int NOUT, bool F32OUT, bool BIAS>
__global__ __launch_bounds__(512, 4) void gemm_fp(const bf16_t* __restrict__ A,
                                                  const bf16_t* __restrict__ Bw,
                                                  void* __restrict__ Cout,
                                                  const float* __restrict__ bias)
{
    constexpr int K   = 1024;
    constexpr int NT  = K / 32;
    constexpr int MI  = BM / 64;
    constexpr int NJ  = BN / 32;
    constexpr int LA  = BM / 128;
    constexpr int LB  = BN / 128;
    constexpr int L   = LA + LB;
    constexpr int ASZ = BM * 64;
    constexpr int BSZ = BN * 64;
    constexpr int NTN = NOUT / BN;

    extern __shared__ char smem[];

    const int tid  = threadIdx.x;
    const int lane = tid & 63;
    const int wave = tid >> 6;
    const int wm   = (wave >> 1) * (BM / 4);
    const int wn   = (wave & 1) * (BN / 2);

    const int nwg = gridDim.x;
    int id = blockIdx.x;
    id = (id & 7) * (nwg >> 3) + (id >> 3);
    const int bm = (id / NTN) * BM;
    const int bn = (id % NTN) * BN;

    const int scol = (((tid & 3) ^ ((tid >> 3) & 3)) * 8);
    const int srow = tid >> 2;
    const bf16_t* Ag = A  + (size_t)(bm + srow) * K + scol;
    const bf16_t* Bg = Bw + (size_t)(bn + srow) * K + scol;

    auto stage = [&](int kt) {
        char* la = smem + (kt % 3) * ASZ + tid * 16;
#pragma unroll
        for (int bl = 0; bl < LA; ++bl)
            GLD16(Ag + (size_t)(bl * 128) * K + kt * 32, la + bl * 8192);
        char* lb = smem + 3 * ASZ + (kt % 3) * BSZ + tid * 16;
#pragma unroll
        for (int bl = 0; bl < LB; ++bl)
            GLD16(Bg + (size_t)(bl * 128) * K + kt * 32, lb + bl * 8192);
    };

    f32x4 acc[MI][NJ] = {};

    stage(0); stage(1);

    int aoff[MI], boff[NJ];
#pragma unroll
    for (int m = 0; m < MI; ++m) {
        const int r = wm + m * 16 + (lane & 15);
        aoff[m] = r * 64 + (((lane >> 4) ^ ((r >> 1) & 3)) * 16);
    }
#pragma unroll
    for (int n = 0; n < NJ; ++n) {
        const int r = wn + n * 16 + (lane & 15);
        boff[n] = r * 64 + (((lane >> 4) ^ ((r >> 1) & 3)) * 16);
    }

    for (int t = 0; t < NT; ++t) {
        if (t < NT - 1) vmwait<3>(); else vmwait<0>();
        __builtin_amdgcn_s_barrier();
        asm volatile("" ::: "memory");

        const char* Ab = smem + (t % 3) * ASZ;
        const char* Bb = smem + 3 * ASZ + (t % 3) * BSZ;

        bf16x8 af[MI], bfr[NJ];
#pragma unroll
        for (int m = 0; m < MI; ++m) af[m]  = *(const bf16x8*)(Ab + aoff[m]);
#pragma unroll
        for (int n = 0; n < NJ; ++n) bfr[n] = *(const bf16x8*)(Bb + boff[n]);

        if (t + 2 < NT) {
            __builtin_amdgcn_sched_barrier(0);
            stage(t + 2);
        }

        __builtin_amdgcn_s_setprio(1);
#pragma unroll
        for (int m = 0; m < MI; ++m)
#pragma unroll
            for (int n = 0; n < NJ; ++n)
                acc[m][n] = __builtin_amdgcn_mfma_f32_16x16x32_bf16(af[m], bfr[n], acc[m][n], 0, 0, 0);
        __builtin_amdgcn_s_setprio(0);
    }

    const int r0 = (lane >> 4) * 4;
    const int c0 = lane & 15;
#pragma unroll
    for (int m = 0; m < MI; ++m) {
#pragma unroll
        for (int n = 0; n < NJ; ++n) {
            const int col = bn + wn + n * 16 + c0;
            float bv = BIAS ? bias[col] : 0.0f;
#pragma unroll
            for (int r = 0; r < 4; ++r) {
                const int row = bm + wm + m * 16 + r0 + r;
                float v = acc[m][n][r] + bv;
                if (F32OUT) ((float*)Cout)[(size_t)row * NOUT + col] = v;
                else        ((bf16_t*)Cout)[(size_t)row * NOUT + col] = (__bf16)v;
            }
        }
    }
}

// ---------------- windowed attention, LDS-staged K/V (R8-proven) ----------------
#define LCH 128
#define KROWS (LCH + 7)
#define RSTR 72

__global__ __launch_bounds__(256) void attn_win_kernel(const bf16_t* __restrict__ QKV,
                                                       const float* __restrict__ conn,
                                                       bf16_t* __restrict__ AO)
{
    __shared__ bf16_t Kl[KROWS * RSTR];
    __shared__ bf16_t Vl[KROWS * RSTR];

    const int tid = threadIdx.x;
    const int blk = blockIdx.x;
    const int lc  = blk & 31;
    const int h   = (blk >> 5) & (NH - 1);
    const int b   = blk >> 9;
    const int l0  = lc * LCH;
    const size_t baseK = (size_t)b * L_SEQ * DQKV + DM + h * DHEAD;
    const size_t baseV = baseK + DM;

#pragma unroll
    for (int it = 0; it < 5; ++it) {
        const int idx = it * 256 + tid;
        if (idx >= KROWS * 8) break;
        const int row = idx >> 3, c = idx & 7;
        const int l = l0 - 3 + row;
        bf16x8 kv = {}, vv = {};
        if ((unsigned)l < L_SEQ) {
            kv = *(const bf16x8*)(QKV + baseK + (size_t)l * DQKV + c * 8);
            vv = *(const bf16x8*)(QKV + baseV + (size_t)l * DQKV + c * 8);
        }
        *(bf16x8*)(Kl + row * RSTR + c * 8) = kv;
        *(bf16x8*)(Vl + row * RSTR + c * 8) = vv;
    }
    __syncthreads();

    const int ll = tid >> 3;
    const int c  = tid & 7;

#pragma unroll
    for (int q = 0; q < LCH / 32; ++q) {
        const int lrow = ll + q * 32;
        const int l    = l0 + lrow;
        const size_t row = (size_t)b * L_SEQ + l;

        const bf16x8 qv = *(const bf16x8*)(QKV + row * DQKV + h * DHEAD + c * 8);

        float s[7];
#pragma unroll
        for (int o = 0; o < 7; ++o) {
            const bf16x8 kv = *(const bf16x8*)(Kl + (lrow + o) * RSTR + c * 8);
            float d = 0.0f;
#pragma unroll
            for (int j = 0; j < 8; ++j) d += (float)qv[j] * (float)kv[j];
            s[o] = d;
        }
#pragma unroll
        for (int m = 1; m < 8; m <<= 1) {
#pragma unroll
            for (int o = 0; o < 7; ++o) s[o] += __shfl_xor(s[o], m, 64);
        }

        float mx = -1e30f;
#pragma unroll
        for (int o = 0; o < 7; ++o) { s[o] *= 0.125f; mx = fmaxf(mx, s[o]); }
        float e[7], Z = 0.0f;
#pragma unroll
        for (int o = 0; o < 7; ++o) { e[o] = expf(s[o] - mx); Z += e[o]; }

        float fw[7], fs = 0.0f;
#pragma unroll
        for (int o = 0; o < 7; ++o) { fw[o] = e[o] * conn[h * 7 + o]; fs += fw[o]; }
        const float inv = 1.0f / (fs + 1e-9f * Z);

        float outv[8] = {};
#pragma unroll
        for (int o = 0; o < 7; ++o) {
            const float w = fw[o] * inv;
            const bf16x8 vv = *(const bf16x8*)(Vl + (lrow + o) * RSTR + c * 8);
#pragma unroll
            for (int j = 0; j < 8; ++j) outv[j] += w * (float)vv[j];
        }

        bf16x8 ov;
#pragma unroll
        for (int j = 0; j < 8; ++j) ov[j] = (__bf16)outv[j];
        *(bf16x8*)(AO + row * DM + h * DHEAD + c * 8) = ov;
    }
}

// ---------------- launch ----------------
extern "C" void kernel_launch(void* const* d_in, const int* in_sizes, int n_in,
                              void* d_out, int out_size, void* d_ws, size_t ws_size,
                              hipStream_t stream)
{
    const float* x   = (const float*)d_in[0];
    const float* wq  = (const float*)d_in[1];
    const float* wk  = (const float*)d_in[2];
    const float* wv  = (const float*)d_in[3];
    const float* wo  = (const float*)d_in[4];
    const float* bo  = (const float*)d_in[5];
    const float* cw1 = (const float*)d_in[6];
    const float* cb1 = (const float*)d_in[7];
    const float* cw2 = (const float*)d_in[8];
    const float* cb2 = (const float*)d_in[9];
    const float* cw3 = (const float*)d_in[10];
    const float* cb3 = (const float*)d_in[11];
    float* out = (float*)d_out;

    char* ws = (char*)d_ws;
    const size_t MB = 1024 * 1024;
    bf16_t* ab    = (bf16_t*)(ws);             // 16 MB attention output
    bf16_t* wqkvb = (bf16_t*)(ws + 16 * MB);   // 6 MB   [3072][1024]
    bf16_t* wob   = (bf16_t*)(ws + 22 * MB);   // 2 MB
    bf16_t* QKV   = (bf16_t*)(ws + 24 * MB);   // 48 MB  [8192][3072]
    float*  conn  = (float*)(ws + 72 * MB);    // 448 B

    (void)hipFuncSetAttribute((const void*)gemm_xa<DQKV>,
                              hipFuncAttributeMaxDynamicSharedMemorySize, 73728);
    (void)hipFuncSetAttribute((const void*)gemm_fp<256, 128, DM, true, true>,
                              hipFuncAttributeMaxDynamicSharedMemorySize, 73728);

    // weight casts + conn only (x is consumed fp32 by gemm_xa)
    fused_cast_kernel<<<2064, 256, 0, stream>>>(wq, wk, wv, wo,
                                                cw1, cb1, cw2, cb2, cw3, cb3,
                                                wqkvb, wob, conn);

    // QKV: fp32-A fused cast GEMM, 32 x 24 = 768 blocks (2 blocks/CU)
    gemm_xa<DQKV><<<768, 512, 73728, stream>>>(x, wqkvb, QKV);

    // attention: 1024 blocks, LDS-staged K/V
    attn_win_kernel<<<NB * NH * (L_SEQ / LCH), 256, 0, stream>>>(QKV, conn, ab);

    // out-proj: 32 x 8 = 256 blocks, proven 256x128 shape
    gemm_fp<256, 128, DM, true, true><<<256, 512, 73728, stream>>>(ab, wob, out, bo);
}

// Round 14
// 128.694 us; speedup vs baseline: 2.4180x; 2.4180x over previous
//
#include <hip/hip_runtime.h>
#include <hip/hip_bf16.h>
#include <math.h>
#include <stdint.h>

#define L_SEQ 4096
#define NB 2
#define NH 16
#define DHEAD 64
#define DM 1024
#define DQKV 3072

typedef __bf16 bf16_t;
typedef __attribute__((ext_vector_type(8))) __bf16 bf16x8;
typedef __attribute__((ext_vector_type(4))) float f32x4;

#define GLD16(gp, lp) __builtin_amdgcn_global_load_lds(                          \
    (const __attribute__((address_space(1))) void*)(gp),                         \
    (__attribute__((address_space(3))) void*)(lp), 16, 0, 0)

template<int N> __device__ __forceinline__ void vmwait() {
    if constexpr (N == 3)      asm volatile("s_waitcnt vmcnt(3)" ::: "memory");
    else if constexpr (N == 2) asm volatile("s_waitcnt vmcnt(2)" ::: "memory");
    else if constexpr (N == 1) asm volatile("s_waitcnt vmcnt(1)" ::: "memory");
    else                       asm volatile("s_waitcnt vmcnt(0)" ::: "memory");
}

// ---------------- fused fp32->bf16 weight casts + conn MLP (R13-proven) ----------------
__device__ __forceinline__ void cast8(const float* src, bf16_t* dst)
{
    const f32x4* ip = (const f32x4*)src;
    f32x4 a = ip[0], b = ip[1];
    bf16x8 o;
    o[0] = (__bf16)a[0]; o[1] = (__bf16)a[1]; o[2] = (__bf16)a[2]; o[3] = (__bf16)a[3];
    o[4] = (__bf16)b[0]; o[5] = (__bf16)b[1]; o[6] = (__bf16)b[2]; o[7] = (__bf16)b[3];
    *(bf16x8*)dst = o;
}

__device__ __forceinline__ float gelu_exact(float z)
{
    return 0.5f * z * (1.0f + erff(z * 0.7071067811865475f));
}

// blocks 0..1535: wq|wk|wv; 1536..2047: wo; 2048..2063: conn
__global__ __launch_bounds__(256) void fused_cast_kernel(
    const float* __restrict__ wq, const float* __restrict__ wk,
    const float* __restrict__ wv, const float* __restrict__ wo,
    const float* __restrict__ cw1, const float* __restrict__ cb1,
    const float* __restrict__ cw2, const float* __restrict__ cb2,
    const float* __restrict__ cw3, const float* __restrict__ cb3,
    bf16_t* __restrict__ wqkvb, bf16_t* __restrict__ wob,
    float* __restrict__ conn)
{
    const int bid = blockIdx.x;
    const int tid = threadIdx.x;
    const int nW = DM * DM / 8;
    if (bid < 1536) {
        int t = bid * 256 + tid;
        const float* src; int lt;
        if (t < nW)          { src = wq; lt = t; }
        else if (t < 2 * nW) { src = wk; lt = t - nW; }
        else                 { src = wv; lt = t - 2 * nW; }
        cast8(src + (size_t)lt * 8, wqkvb + (size_t)t * 8);
    } else if (bid < 2048) {
        int t = (bid - 1536) * 256 + tid;
        cast8(wo + (size_t)t * 8, wob + (size_t)t * 8);
    } else {
        __shared__ float h1[7][32];
        __shared__ float h2[7][32];
        const int h = bid - 2048;
        const int j = tid;
        if (j < 32) {
            for (int w = 0; w < 7; ++w) {
                float pos = (float)w / 6.0f;
                float z = pos * cw1[h * 32 + j] + cb1[h * 32 + j];
                h1[w][j] = gelu_exact(z);
            }
        }
        __syncthreads();
        if (j < 32) {
            for (int w = 0; w < 7; ++w) {
                float z = cb2[h * 32 + j];
                for (int i = 0; i < 32; ++i) z += h1[w][i] * cw2[((size_t)h * 32 + j) * 32 + i];
                h2[w][j] = gelu_exact(z);
            }
        }
        __syncthreads();
        if (j == 0) {
            float cwt[7];
            float mx = -1e30f;
            for (int w = 0; w < 7; ++w) {
                float z = cb3[h];
                for (int i = 0; i < 32; ++i) z += h2[w][i] * cw3[h * 32 + i];
                cwt[w] = z;
                mx = fmaxf(mx, z);
            }
            float Z = 0.0f;
            for (int w = 0; w < 7; ++w) { cwt[w] = expf(cwt[w] - mx); Z += cwt[w]; }
            for (int w = 0; w < 7; ++w) conn[h * 7 + w] = cwt[w] / Z;
        }
    }
}

// ---------------- QKV GEMM, in-kernel fp32->bf16 A conversion (rule-#20-safe) ----------------
// C[8192, NOUT] = cast_bf16(Xf) @ Bw^T.  R11's proven rhythm; A staged via
// regs (STATIC indices only: ar[2][2], all loops unrolled) at distance 1,
// B via global_load_lds at distance 2.
// LEDGER (issue order per tile t: reads -> A(t+1) x4 loads -> B(t+2) gld):
//   entry queue at tile t: [B(t), A(t)x4, B(t+1)]  (6 ops)
//   gate vmcnt(1): drains B(t) + A(t)x4, keeps B(t+1) in flight. NEVER 0 mid-loop.
//   -> writeA(t) (ds_write, regs drained) -> lgkmcnt(0) (publish) -> s_barrier
//   -> reads(t) -> issue A(t+1) | B(t+2) -> MFMA(t).
//   Tail: t=NT-1 entry queue [B(NT-1), A(NT-1)x4] -> vmcnt(0).
// A slot t%3 overwrite: previous tenant tile t-3, readers done 2 barriers ago.
// B slot (t+2)%3 overwrite: tenant t-1, readers ordered by the tile-t barrier.
// Swizzle identical to R11 (0 conflicts measured).
template<int NOUT>
__global__ __launch_bounds__(512, 4) void gemm_xa(const float* __restrict__ Xf,
                                                  const bf16_t* __restrict__ Bw,
                                                  bf16_t* __restrict__ Cout)
{
    constexpr int K   = 1024;
    constexpr int NT  = K / 32;
    constexpr int ASZ = 256 * 64;          // bytes per A K-tile buffer
    constexpr int BSZ = 128 * 64;
    constexpr int NTN = NOUT / 128;

    extern __shared__ char smem[];         // A: 3*ASZ @0, B: 3*BSZ @3*ASZ

    const int tid  = threadIdx.x;
    const int lane = tid & 63;
    const int wave = tid >> 6;
    const int wm   = (wave >> 1) * 64;
    const int wn   = (wave & 1) * 64;

    const int nwg = gridDim.x;
    int id = blockIdx.x;
    id = (id & 7) * (nwg >> 3) + (id >> 3);
    const int bm = (id / NTN) * 256;
    const int bn = (id % NTN) * 128;

    const int scol = (((tid & 3) ^ ((tid >> 3) & 3)) * 8);
    const int srow = tid >> 2;             // 0..127
    const float*  Ax = Xf + (size_t)(bm + srow) * K + scol;
    const bf16_t* Bg = Bw + (size_t)(bn + srow) * K + scol;

    f32x4 ar[2][2];                        // [chunk][half] — STATIC indices only

    auto issueA = [&](int kt) {
#pragma unroll
        for (int c = 0; c < 2; ++c) {
            const float* p = Ax + (size_t)(c * 128) * K + kt * 32;
            ar[c][0] = *(const f32x4*)p;
            ar[c][1] = *(const f32x4*)(p + 4);
        }
    };
    auto writeA = [&](int kt) {
        char* la = smem + (kt % 3) * ASZ + tid * 16;
#pragma unroll
        for (int c = 0; c < 2; ++c) {
            f32x4 lo = ar[c][0], hi = ar[c][1];
            bf16x8 o;
            o[0] = (__bf16)lo[0]; o[1] = (__bf16)lo[1];
            o[2] = (__bf16)lo[2]; o[3] = (__bf16)lo[3];
            o[4] = (__bf16)hi[0]; o[5] = (__bf16)hi[1];
            o[6] = (__bf16)hi[2]; o[7] = (__bf16)hi[3];
            *(bf16x8*)(la + c * 8192) = o;     // ds_write_b128
        }
    };
    auto stageB = [&](int kt) {
        char* lb = smem + 3 * ASZ + (kt % 3) * BSZ + tid * 16;
        GLD16(Bg + (size_t)kt * 32, lb);
    };

    f32x4 acc[4][4] = {};

    // prologue: establish entry-queue invariant for tile 0: [B(0), A(0)x4, B(1)]
    stageB(0);
    asm volatile("" ::: "memory");
    issueA(0);
    asm volatile("" ::: "memory");
    stageB(1);

    int aoff[4], boff[4];
#pragma unroll
    for (int m = 0; m < 4; ++m) {
        const int r = wm + m * 16 + (lane & 15);
        aoff[m] = r * 64 + (((lane >> 4) ^ ((r >> 1) & 3)) * 16);
    }
#pragma unroll
    for (int n = 0; n < 4; ++n) {
        const int r = wn + n * 16 + (lane & 15);
        boff[n] = r * 64 + (((lane >> 4) ^ ((r >> 1) & 3)) * 16);
    }

    for (int t = 0; t < NT; ++t) {
        if (t < NT - 1) vmwait<1>(); else vmwait<0>();
        writeA(t);                                           // regs drained above
        asm volatile("s_waitcnt lgkmcnt(0)" ::: "memory");   // publish A ds_writes
        __builtin_amdgcn_s_barrier();
        asm volatile("" ::: "memory");

        const char* Ab = smem + (t % 3) * ASZ;
        const char* Bb = smem + 3 * ASZ + (t % 3) * BSZ;

        bf16x8 af[4], bfr[4];
#pragma unroll
        for (int m = 0; m < 4; ++m) af[m]  = *(const bf16x8*)(Ab + aoff[m]);
#pragma unroll
        for (int n = 0; n < 4; ++n) bfr[n] = *(const bf16x8*)(Bb + boff[n]);

        if (t + 1 < NT) {
            __builtin_amdgcn_sched_barrier(0);   // reads issue before new loads
            issueA(t + 1);
            asm volatile("" ::: "memory");       // keep A-before-B issue order
            if (t + 2 < NT) stageB(t + 2);
        }

        __builtin_amdgcn_s_setprio(1);
#pragma unroll
        for (int m = 0; m < 4; ++m)
#pragma unroll
            for (int n = 0; n < 4; ++n)
                acc[m][n] = __builtin_amdgcn_mfma_f32_16x16x32_bf16(af[m], bfr[n], acc[m][n], 0, 0, 0);
        __builtin_amdgcn_s_setprio(0);
    }

    const int r0 = (lane >> 4) * 4;
    const int c0 = lane & 15;
#pragma unroll
    for (int m = 0; m < 4; ++m) {
#pragma unroll
        for (int n = 0; n < 4; ++n) {
            const int col = bn + wn + n * 16 + c0;
#pragma unroll
            for (int r = 0; r < 4; ++r) {
                const int row = bm + wm + m * 16 + r0 + r;
                Cout[(size_t)row * NOUT + col] = (__bf16)acc[m][n][r];
            }
        }
    }
}

// ---------------- R5/R8/R11-proven coarse GEMM (out-proj) ----------------
template<int BM, int BN, int NOUT, bool F32OUT, bool BIAS>
__global__ __launch_bounds__(512, 4) void gemm_fp(const bf16_t* __restrict__ A,
                                                  const bf16_t* __restrict__ Bw,
                                                  void* __restrict__ Cout,
                                                  const float* __restrict__ bias)
{
    constexpr int K   = 1024;
    constexpr int NT  = K / 32;
    constexpr int MI  = BM / 64;
    constexpr int NJ  = BN / 32;
    constexpr int LA  = BM / 128;
    constexpr int LB  = BN / 128;
    constexpr int L   = LA + LB;
    constexpr int ASZ = BM * 64;
    constexpr int BSZ = BN * 64;
    constexpr int NTN = NOUT / BN;

    extern __shared__ char smem[];

    const int tid  = threadIdx.x;
    const int lane = tid & 63;
    const int wave = tid >> 6;
    const int wm   = (wave >> 1) * (BM / 4);
    const int wn   = (wave & 1) * (BN / 2);

    const int nwg = gridDim.x;
    int id = blockIdx.x;
    id = (id & 7) * (nwg >> 3) + (id >> 3);
    const int bm = (id / NTN) * BM;
    const int bn = (id % NTN) * BN;

    const int scol = (((tid & 3) ^ ((tid >> 3) & 3)) * 8);
    const int srow = tid >> 2;
    const bf16_t* Ag = A  + (size_t)(bm + srow) * K + scol;
    const bf16_t* Bg = Bw + (size_t)(bn + srow) * K + scol;

    auto stage = [&](int kt) {
        char* la = smem + (kt % 3) * ASZ + tid * 16;
#pragma unroll
        for (int bl = 0; bl < LA; ++bl)
            GLD16(Ag + (size_t)(bl * 128) * K + kt * 32, la + bl * 8192);
        char* lb = smem + 3 * ASZ + (kt % 3) * BSZ + tid * 16;
#pragma unroll
        for (int bl = 0; bl < LB; ++bl)
            GLD16(Bg + (size_t)(bl * 128) * K + kt * 32, lb + bl * 8192);
    };

    f32x4 acc[MI][NJ] = {};

    stage(0); stage(1);

    int aoff[MI], boff[NJ];
#pragma unroll
    for (int m = 0; m < MI; ++m) {
        const int r = wm + m * 16 + (lane & 15);
        aoff[m] = r * 64 + (((lane >> 4) ^ ((r >> 1) & 3)) * 16);
    }
#pragma unroll
    for (int n = 0; n < NJ; ++n) {
        const int r = wn + n * 16 + (lane & 15);
        boff[n] = r * 64 + (((lane >> 4) ^ ((r >> 1) & 3)) * 16);
    }

    for (int t = 0; t < NT; ++t) {
        if (t < NT - 1) vmwait<3>(); else vmwait<0>();
        __builtin_amdgcn_s_barrier();
        asm volatile("" ::: "memory");

        const char* Ab = smem + (t % 3) * ASZ;
        const char* Bb = smem + 3 * ASZ + (t % 3) * BSZ;

        bf16x8 af[MI], bfr[NJ];
#pragma unroll
        for (int m = 0; m < MI; ++m) af[m]  = *(const bf16x8*)(Ab + aoff[m]);
#pragma unroll
        for (int n = 0; n < NJ; ++n) bfr[n] = *(const bf16x8*)(Bb + boff[n]);

        if (t + 2 < NT) {
            __builtin_amdgcn_sched_barrier(0);
            stage(t + 2);
        }

        __builtin_amdgcn_s_setprio(1);
#pragma unroll
        for (int m = 0; m < MI; ++m)
#pragma unroll
            for (int n = 0; n < NJ; ++n)
                acc[m][n] = __builtin_amdgcn_mfma_f32_16x16x32_bf16(af[m], bfr[n], acc[m][n], 0, 0, 0);
        __builtin_amdgcn_s_setprio(0);
    }

    const int r0 = (lane >> 4) * 4;
    const int c0 = lane & 15;
#pragma unroll
    for (int m = 0; m < MI; ++m) {
#pragma unroll
        for (int n = 0; n < NJ; ++n) {
            const int col = bn + wn + n * 16 + c0;
            float bv = BIAS ? bias[col] : 0.0f;
#pragma unroll
            for (int r = 0; r < 4; ++r) {
                const int row = bm + wm + m * 16 + r0 + r;
                float v = acc[m][n][r] + bv;
                if (F32OUT) ((float*)Cout)[(size_t)row * NOUT + col] = v;
                else        ((bf16_t*)Cout)[(size_t)row * NOUT + col] = (__bf16)v;
            }
        }
    }
}

// ---------------- windowed attention, LDS-staged K/V (R8-proven) ----------------
#define LCH 128
#define KROWS (LCH + 7)
#define RSTR 72

__global__ __launch_bounds__(256) void attn_win_kernel(const bf16_t* __restrict__ QKV,
                                                       const float* __restrict__ conn,
                                                       bf16_t* __restrict__ AO)
{
    __shared__ bf16_t Kl[KROWS * RSTR];
    __shared__ bf16_t Vl[KROWS * RSTR];

    const int tid = threadIdx.x;
    const int blk = blockIdx.x;
    const int lc  = blk & 31;
    const int h   = (blk >> 5) & (NH - 1);
    const int b   = blk >> 9;
    const int l0  = lc * LCH;
    const size_t baseK = (size_t)b * L_SEQ * DQKV + DM + h * DHEAD;
    const size_t baseV = baseK + DM;

#pragma unroll
    for (int it = 0; it < 5; ++it) {
        const int idx = it * 256 + tid;
        if (idx >= KROWS * 8) break;
        const int row = idx >> 3, c = idx & 7;
        const int l = l0 - 3 + row;
        bf16x8 kv = {}, vv = {};
        if ((unsigned)l < L_SEQ) {
            kv = *(const bf16x8*)(QKV + baseK + (size_t)l * DQKV + c * 8);
            vv = *(const bf16x8*)(QKV + baseV + (size_t)l * DQKV + c * 8);
        }
        *(bf16x8*)(Kl + row * RSTR + c * 8) = kv;
        *(bf16x8*)(Vl + row * RSTR + c * 8) = vv;
    }
    __syncthreads();

    const int ll = tid >> 3;
    const int c  = tid & 7;

#pragma unroll
    for (int q = 0; q < LCH / 32; ++q) {
        const int lrow = ll + q * 32;
        const int l    = l0 + lrow;
        const size_t row = (size_t)b * L_SEQ + l;

        const bf16x8 qv = *(const bf16x8*)(QKV + row * DQKV + h * DHEAD + c * 8);

        float s[7];
#pragma unroll
        for (int o = 0; o < 7; ++o) {
            const bf16x8 kv = *(const bf16x8*)(Kl + (lrow + o) * RSTR + c * 8);
            float d = 0.0f;
#pragma unroll
            for (int j = 0; j < 8; ++j) d += (float)qv[j] * (float)kv[j];
            s[o] = d;
        }
#pragma unroll
        for (int m = 1; m < 8; m <<= 1) {
#pragma unroll
            for (int o = 0; o < 7; ++o) s[o] += __shfl_xor(s[o], m, 64);
        }

        float mx = -1e30f;
#pragma unroll
        for (int o = 0; o < 7; ++o) { s[o] *= 0.125f; mx = fmaxf(mx, s[o]); }
        float e[7], Z = 0.0f;
#pragma unroll
        for (int o = 0; o < 7; ++o) { e[o] = expf(s[o] - mx); Z += e[o]; }

        float fw[7], fs = 0.0f;
#pragma unroll
        for (int o = 0; o < 7; ++o) { fw[o] = e[o] * conn[h * 7 + o]; fs += fw[o]; }
        const float inv = 1.0f / (fs + 1e-9f * Z);

        float outv[8] = {};
#pragma unroll
        for (int o = 0; o < 7; ++o) {
            const float w = fw[o] * inv;
            const bf16x8 vv = *(const bf16x8*)(Vl + (lrow + o) * RSTR + c * 8);
#pragma unroll
            for (int j = 0; j < 8; ++j) outv[j] += w * (float)vv[j];
        }

        bf16x8 ov;
#pragma unroll
        for (int j = 0; j < 8; ++j) ov[j] = (__bf16)outv[j];
        *(bf16x8*)(AO + row * DM + h * DHEAD + c * 8) = ov;
    }
}

// ---------------- launch ----------------
extern "C" void kernel_launch(void* const* d_in, const int* in_sizes, int n_in,
                              void* d_out, int out_size, void* d_ws, size_t ws_size,
                              hipStream_t stream)
{
    const float* x   = (const float*)d_in[0];
    const float* wq  = (const float*)d_in[1];
    const float* wk  = (const float*)d_in[2];
    const float* wv  = (const float*)d_in[3];
    const float* wo  = (const float*)d_in[4];
    const float* bo  = (const float*)d_in[5];
    const float* cw1 = (const float*)d_in[6];
    const float* cb1 = (const float*)d_in[7];
    const float* cw2 = (const float*)d_in[8];
    const float* cb2 = (const float*)d_in[9];
    const float* cw3 = (const float*)d_in[10];
    const float* cb3 = (const float*)d_in[11];
    float* out = (float*)d_out;

    char* ws = (char*)d_ws;
    const size_t MB = 1024 * 1024;
    bf16_t* ab    = (bf16_t*)(ws);             // 16 MB attention output
    bf16_t* wqkvb = (bf16_t*)(ws + 16 * MB);   // 6 MB   [3072][1024]
    bf16_t* wob   = (bf16_t*)(ws + 22 * MB);   // 2 MB
    bf16_t* QKV   = (bf16_t*)(ws + 24 * MB);   // 48 MB  [8192][3072]
    float*  conn  = (float*)(ws + 72 * MB);    // 448 B

    (void)hipFuncSetAttribute((const void*)gemm_xa<DQKV>,
                              hipFuncAttributeMaxDynamicSharedMemorySize, 73728);
    (void)hipFuncSetAttribute((const void*)gemm_fp<256, 128, DM, true, true>,
                              hipFuncAttributeMaxDynamicSharedMemorySize, 73728);

    // weight casts + conn only (x is consumed fp32 by gemm_xa)
    fused_cast_kernel<<<2064, 256, 0, stream>>>(wq, wk, wv, wo,
                                                cw1, cb1, cw2, cb2, cw3, cb3,
                                                wqkvb, wob, conn);

    // QKV: fp32-A fused cast GEMM, 32 x 24 = 768 blocks (2 blocks/CU)
    gemm_xa<DQKV><<<768, 512, 73728, stream>>>(x, wqkvb, QKV);

    // attention: 1024 blocks, LDS-staged K/V
    attn_win_kernel<<<NB * NH * (L_SEQ / LCH), 256, 0, stream>>>(QKV, conn, ab);

    // out-proj: 32 x 8 = 256 blocks, proven 256x128 shape
    gemm_fp<256, 128, DM, true, true><<<256, 512, 73728, stream>>>(ab, wob, out, bo);
}

// Round 15
// 117.971 us; speedup vs baseline: 2.6378x; 1.0909x over previous
//
#include <hip/hip_runtime.h>
#include <hip/hip_bf16.h>
#include <math.h>
#include <stdint.h>

#define L_SEQ 4096
#define NB 2
#define NH 16
#define DHEAD 64
#define DM 1024
#define DQKV 3072

typedef __bf16 bf16_t;
typedef __attribute__((ext_vector_type(8))) __bf16 bf16x8;
typedef __attribute__((ext_vector_type(4))) float f32x4;

#define GLD16(gp, lp) __builtin_amdgcn_global_load_lds(                          \
    (const __attribute__((address_space(1))) void*)(gp),                         \
    (__attribute__((address_space(3))) void*)(lp), 16, 0, 0)

template<int N> __device__ __forceinline__ void vmwait() {
    if constexpr (N == 3)      asm volatile("s_waitcnt vmcnt(3)" ::: "memory");
    else if constexpr (N == 2) asm volatile("s_waitcnt vmcnt(2)" ::: "memory");
    else                       asm volatile("s_waitcnt vmcnt(0)" ::: "memory");
}

// ---------------- fused fp32->bf16 casts + conn MLP ----------------
__device__ __forceinline__ void cast8(const float* src, bf16_t* dst)
{
    const f32x4* ip = (const f32x4*)src;
    f32x4 a = ip[0], b = ip[1];
    bf16x8 o;
    o[0] = (__bf16)a[0]; o[1] = (__bf16)a[1]; o[2] = (__bf16)a[2]; o[3] = (__bf16)a[3];
    o[4] = (__bf16)b[0]; o[5] = (__bf16)b[1]; o[6] = (__bf16)b[2]; o[7] = (__bf16)b[3];
    *(bf16x8*)dst = o;
}

__device__ __forceinline__ float gelu_exact(float z)
{
    return 0.5f * z * (1.0f + erff(z * 0.7071067811865475f));
}

// blocks 0..4095: x; 4096..5631: wq|wk|wv; 5632..6143: wo; 6144..6159: conn
__global__ __launch_bounds__(256) void fused_cast_kernel(
    const float* __restrict__ x,  const float* __restrict__ wq,
    const float* __restrict__ wk, const float* __restrict__ wv,
    const float* __restrict__ wo,
    const float* __restrict__ cw1, const float* __restrict__ cb1,
    const float* __restrict__ cw2, const float* __restrict__ cb2,
    const float* __restrict__ cw3, const float* __restrict__ cb3,
    bf16_t* __restrict__ xb, bf16_t* __restrict__ wqkvb, bf16_t* __restrict__ wob,
    float* __restrict__ conn)
{
    const int bid = blockIdx.x;
    const int tid = threadIdx.x;
    const int nW = DM * DM / 8;
    if (bid < 4096) {
        int t = bid * 256 + tid;
        cast8(x + (size_t)t * 8, xb + (size_t)t * 8);
    } else if (bid < 5632) {
        int t = (bid - 4096) * 256 + tid;
        const float* src; int lt;
        if (t < nW)          { src = wq; lt = t; }
        else if (t < 2 * nW) { src = wk; lt = t - nW; }
        else                 { src = wv; lt = t - 2 * nW; }
        cast8(src + (size_t)lt * 8, wqkvb + (size_t)t * 8);
    } else if (bid < 6144) {
        int t = (bid - 5632) * 256 + tid;
        cast8(wo + (size_t)t * 8, wob + (size_t)t * 8);
    } else {
        __shared__ float h1[7][32];
        __shared__ float h2[7][32];
        const int h = bid - 6144;
        const int j = tid;
        if (j < 32) {
            for (int w = 0; w < 7; ++w) {
                float pos = (float)w / 6.0f;
                float z = pos * cw1[h * 32 + j] + cb1[h * 32 + j];
                h1[w][j] = gelu_exact(z);
            }
        }
        __syncthreads();
        if (j < 32) {
            for (int w = 0; w < 7; ++w) {
                float z = cb2[h * 32 + j];
                for (int i = 0; i < 32; ++i) z += h1[w][i] * cw2[((size_t)h * 32 + j) * 32 + i];
                h2[w][j] = gelu_exact(z);
            }
        }
        __syncthreads();
        if (j == 0) {
            float cwt[7];
            float mx = -1e30f;
            for (int w = 0; w < 7; ++w) {
                float z = cb3[h];
                for (int i = 0; i < 32; ++i) z += h2[w][i] * cw3[h * 32 + i];
                cwt[w] = z;
                mx = fmaxf(mx, z);
            }
            float Z = 0.0f;
            for (int w = 0; w < 7; ++w) { cwt[w] = expf(cwt[w] - mx); Z += cwt[w]; }
            for (int w = 0; w < 7; ++w) conn[h * 7 + w] = cwt[w] / Z;
        }
    }
}

// ---------------- BMxBN bf16 GEMM, BK=32, triple-buffer (R8/R11-proven) ----------------
// C[M=8192, NOUT] = A @ Bw^T (+bias).  512 thr = 8 waves as 4M x 2N.
// Per K-tile t: vmcnt(L) -> s_barrier -> 8 ds_read_b128 -> stage tile t+2 ->
// setprio(1) 16 MFMA setprio(0).  Swizzle: dest 16B slot sd holds source slot
// sd^((row>>1)&3); reads use slot^((row>>1)&3) => 2-way banks (0 conflicts measured).
template<int BM, int BN, int NOUT, bool F32OUT, bool BIAS>
__global__ __launch_bounds__(512, 4) void gemm_fp(const bf16_t* __restrict__ A,
                                                  const bf16_t* __restrict__ Bw,
                                                  void* __restrict__ Cout,
                                                  const float* __restrict__ bias)
{
    constexpr int K   = 1024;
    constexpr int NT  = K / 32;
    constexpr int MI  = BM / 64;
    constexpr int NJ  = BN / 32;
    constexpr int LA  = BM / 128;
    constexpr int LB  = BN / 128;
    constexpr int L   = LA + LB;
    constexpr int ASZ = BM * 64;
    constexpr int BSZ = BN * 64;
    constexpr int NTN = NOUT / BN;

    extern __shared__ char smem[];

    const int tid  = threadIdx.x;
    const int lane = tid & 63;
    const int wave = tid >> 6;
    const int wm   = (wave >> 1) * (BM / 4);
    const int wn   = (wave & 1) * (BN / 2);

    const int nwg = gridDim.x;
    int id = blockIdx.x;
    id = (id & 7) * (nwg >> 3) + (id >> 3);
    const int bm = (id / NTN) * BM;
    const int bn = (id % NTN) * BN;

    const int scol = (((tid & 3) ^ ((tid >> 3) & 3)) * 8);
    const int srow = tid >> 2;
    const bf16_t* Ag = A  + (size_t)(bm + srow) * K + scol;
    const bf16_t* Bg = Bw + (size_t)(bn + srow) * K + scol;

    auto stage = [&](int kt) {
        char* la = smem + (kt % 3) * ASZ + tid * 16;
#pragma unroll
        for (int bl = 0; bl < LA; ++bl)
            GLD16(Ag + (size_t)(bl * 128) * K + kt * 32, la + bl * 8192);
        char* lb = smem + 3 * ASZ + (kt % 3) * BSZ + tid * 16;
#pragma unroll
        for (int bl = 0; bl < LB; ++bl)
            GLD16(Bg + (size_t)(bl * 128) * K + kt * 32, lb + bl * 8192);
    };

    f32x4 acc[MI][NJ] = {};

    stage(0); stage(1);

    int aoff[MI], boff[NJ];
#pragma unroll
    for (int m = 0; m < MI; ++m) {
        const int r = wm + m * 16 + (lane & 15);
        aoff[m] = r * 64 + (((lane >> 4) ^ ((r >> 1) & 3)) * 16);
    }
#pragma unroll
    for (int n = 0; n < NJ; ++n) {
        const int r = wn + n * 16 + (lane & 15);
        boff[n] = r * 64 + (((lane >> 4) ^ ((r >> 1) & 3)) * 16);
    }

    for (int t = 0; t < NT; ++t) {
        if (t < NT - 1) vmwait<L>(); else vmwait<0>();
        __builtin_amdgcn_s_barrier();
        asm volatile("" ::: "memory");

        const char* Ab = smem + (t % 3) * ASZ;
        const char* Bb = smem + 3 * ASZ + (t % 3) * BSZ;

        bf16x8 af[MI], bfr[NJ];
#pragma unroll
        for (int m = 0; m < MI; ++m) af[m]  = *(const bf16x8*)(Ab + aoff[m]);
#pragma unroll
        for (int n = 0; n < NJ; ++n) bfr[n] = *(const bf16x8*)(Bb + boff[n]);

        if (t + 2 < NT) {
            __builtin_amdgcn_sched_barrier(0);
            stage(t + 2);
        }

        __builtin_amdgcn_s_setprio(1);
#pragma unroll
        for (int m = 0; m < MI; ++m)
#pragma unroll
            for (int n = 0; n < NJ; ++n)
                acc[m][n] = __builtin_amdgcn_mfma_f32_16x16x32_bf16(af[m], bfr[n], acc[m][n], 0, 0, 0);
        __builtin_amdgcn_s_setprio(0);
    }

    const int r0 = (lane >> 4) * 4;
    const int c0 = lane & 15;
#pragma unroll
    for (int m = 0; m < MI; ++m) {
#pragma unroll
        for (int n = 0; n < NJ; ++n) {
            const int col = bn + wn + n * 16 + c0;
            float bv = BIAS ? bias[col] : 0.0f;
#pragma unroll
            for (int r = 0; r < 4; ++r) {
                const int row = bm + wm + m * 16 + r0 + r;
                float v = acc[m][n][r] + bv;
                if (F32OUT) ((float*)Cout)[(size_t)row * NOUT + col] = v;
                else        ((bf16_t*)Cout)[(size_t)row * NOUT + col] = (__bf16)v;
            }
        }
    }
}

// ---------------- windowed attention, LDS-staged K/V (R8-proven) ----------------
#define LCH 128
#define KROWS (LCH + 7)
#define RSTR 72

__global__ __launch_bounds__(256) void attn_win_kernel(const bf16_t* __restrict__ QKV,
                                                       const float* __restrict__ conn,
                                                       bf16_t* __restrict__ AO)
{
    __shared__ bf16_t Kl[KROWS * RSTR];
    __shared__ bf16_t Vl[KROWS * RSTR];

    const int tid = threadIdx.x;
    const int blk = blockIdx.x;
    const int lc  = blk & 31;
    const int h   = (blk >> 5) & (NH - 1);
    const int b   = blk >> 9;
    const int l0  = lc * LCH;
    const size_t baseK = (size_t)b * L_SEQ * DQKV + DM + h * DHEAD;
    const size_t baseV = baseK + DM;

#pragma unroll
    for (int it = 0; it < 5; ++it) {
        const int idx = it * 256 + tid;
        if (idx >= KROWS * 8) break;
        const int row = idx >> 3, c = idx & 7;
        const int l = l0 - 3 + row;
        bf16x8 kv = {}, vv = {};
        if ((unsigned)l < L_SEQ) {
            kv = *(const bf16x8*)(QKV + baseK + (size_t)l * DQKV + c * 8);
            vv = *(const bf16x8*)(QKV + baseV + (size_t)l * DQKV + c * 8);
        }
        *(bf16x8*)(Kl + row * RSTR + c * 8) = kv;
        *(bf16x8*)(Vl + row * RSTR + c * 8) = vv;
    }
    __syncthreads();

    const int ll = tid >> 3;
    const int c  = tid & 7;

#pragma unroll
    for (int q = 0; q < LCH / 32; ++q) {
        const int lrow = ll + q * 32;
        const int l    = l0 + lrow;
        const size_t row = (size_t)b * L_SEQ + l;

        const bf16x8 qv = *(const bf16x8*)(QKV + row * DQKV + h * DHEAD + c * 8);

        float s[7];
#pragma unroll
        for (int o = 0; o < 7; ++o) {
            const bf16x8 kv = *(const bf16x8*)(Kl + (lrow + o) * RSTR + c * 8);
            float d = 0.0f;
#pragma unroll
            for (int j = 0; j < 8; ++j) d += (float)qv[j] * (float)kv[j];
            s[o] = d;
        }
#pragma unroll
        for (int m = 1; m < 8; m <<= 1) {
#pragma unroll
            for (int o = 0; o < 7; ++o) s[o] += __shfl_xor(s[o], m, 64);
        }

        float mx = -1e30f;
#pragma unroll
        for (int o = 0; o < 7; ++o) { s[o] *= 0.125f; mx = fmaxf(mx, s[o]); }
        float e[7], Z = 0.0f;
#pragma unroll
        for (int o = 0; o < 7; ++o) { e[o] = expf(s[o] - mx); Z += e[o]; }

        float fw[7], fs = 0.0f;
#pragma unroll
        for (int o = 0; o < 7; ++o) { fw[o] = e[o] * conn[h * 7 + o]; fs += fw[o]; }
        const float inv = 1.0f / (fs + 1e-9f * Z);

        float outv[8] = {};
#pragma unroll
        for (int o = 0; o < 7; ++o) {
            const float w = fw[o] * inv;
            const bf16x8 vv = *(const bf16x8*)(Vl + (lrow + o) * RSTR + c * 8);
#pragma unroll
            for (int j = 0; j < 8; ++j) outv[j] += w * (float)vv[j];
        }

        bf16x8 ov;
#pragma unroll
        for (int j = 0; j < 8; ++j) ov[j] = (__bf16)outv[j];
        *(bf16x8*)(AO + row * DM + h * DHEAD + c * 8) = ov;
    }
}

// ---------------- launch ----------------
extern "C" void kernel_launch(void* const* d_in, const int* in_sizes, int n_in,
                              void* d_out, int out_size, void* d_ws, size_t ws_size,
                              hipStream_t stream)
{
    const float* x   = (const float*)d_in[0];
    const float* wq  = (const float*)d_in[1];
    const float* wk  = (const float*)d_in[2];
    const float* wv  = (const float*)d_in[3];
    const float* wo  = (const float*)d_in[4];
    const float* bo  = (const float*)d_in[5];
    const float* cw1 = (const float*)d_in[6];
    const float* cb1 = (const float*)d_in[7];
    const float* cw2 = (const float*)d_in[8];
    const float* cb2 = (const float*)d_in[9];
    const float* cw3 = (const float*)d_in[10];
    const float* cb3 = (const float*)d_in[11];
    float* out = (float*)d_out;

    char* ws = (char*)d_ws;
    const size_t MB = 1024 * 1024;
    bf16_t* xb    = (bf16_t*)(ws);             // 16 MB; reused as attention output
    bf16_t* wqkvb = (bf16_t*)(ws + 16 * MB);   // 6 MB   [3072][1024]
    bf16_t* wob   = (bf16_t*)(ws + 22 * MB);   // 2 MB
    bf16_t* QKV   = (bf16_t*)(ws + 24 * MB);   // 48 MB  [8192][3072]
    float*  conn  = (float*)(ws + 72 * MB);    // 448 B

    (void)hipFuncSetAttribute((const void*)gemm_fp<256, 128, DQKV, false, false>,
                              hipFuncAttributeMaxDynamicSharedMemorySize, 73728);
    (void)hipFuncSetAttribute((const void*)gemm_fp<256, 128, DM, true, true>,
                              hipFuncAttributeMaxDynamicSharedMemorySize, 73728);

    // casts + conn in one launch
    fused_cast_kernel<<<6160, 256, 0, stream>>>(x, wq, wk, wv, wo,
                                                cw1, cb1, cw2, cb2, cw3, cb3,
                                                xb, wqkvb, wob, conn);

    // QKV: 32 M-tiles x 24 N-tiles = 768 blocks (2 blocks/CU)
    gemm_fp<256, 128, DQKV, false, false><<<768, 512, 73728, stream>>>(xb, wqkvb, QKV, nullptr);

    // attention: 1024 blocks, LDS-staged K/V
    attn_win_kernel<<<NB * NH * (L_SEQ / LCH), 256, 0, stream>>>(QKV, conn, xb);

    // out-proj: 32 x 8 = 256 blocks, proven 256x128 shape
    gemm_fp<256, 128, DM, true, true><<<256, 512, 73728, stream>>>(xb, wob, out, bo);
}